// Round 1
// baseline (97.839 us; speedup 1.0000x reference)
//
#include <hip/hip_runtime.h>

// MLS warp: B batches, C=68 control points, 32x32 grid, fp32.
// Per pixel (i,j), v=(j,i):
//   w_c = 1/(|pf_c - v|^2 + 1e-8)           (pf = dp coord-swapped)
//   p*  = sum(w pf)/sum(w); q* = sum(w qf)/sum(w)   (qf = sp coord-swapped)
//   M   = sum(w_raw h h^T), h_c = pf_c - p*         (un-normalized: 1/sumw
//   K   = sum(w_raw h (qf - q*)^T)                   cancels in g^T M^-1 K)
//   g   = (v - p*)^T M^-1 ;  t = g^T K + q*
//   zero where t<0 or t>31.
#define NC 68

__global__ __launch_bounds__(256) void mls_kernel(
    const float* __restrict__ sp, const float* __restrict__ dp,
    float* __restrict__ out)
{
  const int b   = blockIdx.x >> 2;
  const int pix = ((blockIdx.x & 3) << 8) | threadIdx.x;   // 0..1023
  const float vx = (float)(pix & 31);   // column index j  (v[0])
  const float vy = (float)(pix >> 5);   // row index i     (v[1])

  // Block-uniform base pointers -> compiler emits s_load (scalar cache).
  const float* __restrict__ spb = sp + b * (NC * 2);
  const float* __restrict__ dpb = dp + b * (NC * 2);

  // Pass 1: raw weights, weighted sums for p*, q*.
  float w[NC];
  float wsum = 0.f, psr0 = 0.f, psr1 = 0.f, qsr0 = 0.f, qsr1 = 0.f;
#pragma unroll
  for (int c = 0; c < NC; ++c) {
    // coord swap: pf[:,0]=dp[:,1], pf[:,1]=dp[:,0]; same for qf/sp.
    // (.astype(int16) in ref is identity: inputs are exact ints 0..31)
    const float pf0 = dpb[2 * c + 1];
    const float pf1 = dpb[2 * c + 0];
    const float qf0 = spb[2 * c + 1];
    const float qf1 = spb[2 * c + 0];
    const float dx = pf0 - vx, dy = pf1 - vy;
    const float d2 = dx * dx + dy * dy + 1e-8f;
    const float wc = 1.0f / d2;          // IEEE divide (match ref numerics)
    w[c] = wc;
    wsum += wc;
    psr0 += wc * pf0; psr1 += wc * pf1;
    qsr0 += wc * qf0; qsr1 += wc * qf1;
  }
  const float ps0 = psr0 / wsum, ps1 = psr1 / wsum;
  const float qs0 = qsr0 / wsum, qs1 = qsr1 / wsum;

  // Pass 2: un-normalized 2x2 covariance M and cross matrix K.
  float m00 = 0.f, m01 = 0.f, m11 = 0.f;
  float K00 = 0.f, K01 = 0.f, K10 = 0.f, K11 = 0.f;
#pragma unroll
  for (int c = 0; c < NC; ++c) {
    const float pf0 = dpb[2 * c + 1];
    const float pf1 = dpb[2 * c + 0];
    const float qf0 = spb[2 * c + 1];
    const float qf1 = spb[2 * c + 0];
    const float h0 = pf0 - ps0, h1 = pf1 - ps1;
    const float wc = w[c];
    const float wh0 = wc * h0, wh1 = wc * h1;
    m00 += wh0 * h0; m01 += wh0 * h1; m11 += wh1 * h1;
    const float e0 = qf0 - qs0, e1 = qf1 - qs1;
    K00 += wh0 * e0; K01 += wh0 * e1;
    K10 += wh1 * e0; K11 += wh1 * e1;
  }

  // 2x2 inverse (adjugate), g = u^T M^-1, t = g^T K + q*.
  const float det  = m00 * m11 - m01 * m01;
  const float idet = 1.0f / det;
  const float i00 = m11 * idet, i01 = -m01 * idet, i11 = m00 * idet;
  const float u0 = vx - ps0, u1 = vy - ps1;
  const float g0 = u0 * i00 + u1 * i01;
  const float g1 = u0 * i01 + u1 * i11;
  float t0 = g0 * K00 + g1 * K10 + qs0;
  float t1 = g0 * K01 + g1 * K11 + qs1;

  // Out-of-range pixels zeroed (NOT clipped), matching reference order.
  if (t0 < 0.f || t0 > 31.f) t0 = 0.f;
  if (t1 < 0.f || t1 > 31.f) t1 = 0.f;

  // out layout (B, 2, 32, 32)
  out[b * 2048 + pix]        = t0;
  out[b * 2048 + 1024 + pix] = t1;
}

extern "C" void kernel_launch(void* const* d_in, const int* in_sizes, int n_in,
                              void* d_out, int out_size, void* d_ws, size_t ws_size,
                              hipStream_t stream) {
  const float* sp = (const float*)d_in[0];
  const float* dp = (const float*)d_in[1];
  float* out = (float*)d_out;
  const int B = in_sizes[0] / (NC * 2);   // 512
  mls_kernel<<<dim3(B * 4), dim3(256), 0, stream>>>(sp, dp, out);
}